// Round 5
// baseline (282.602 us; speedup 1.0000x reference)
//
#include <hip/hip_runtime.h>
#include <math.h>

// Problem constants (match reference file)
#define NB 16
#define NPIX 1048576                       // 1024*1024
#define BINS 2048                          // histogram bins (exact sums per bin)
#define COPIES 2                           // LDS histogram replication (lane&1)
#define CHUNKS 64                          // blocks per sample in pass A
#define TPB_A 512
#define PIX_PER_BLOCK (NPIX / CHUNKS)      // 16384
#define PPT 4                              // pixels per thread per iter (one float4/stream)
#define ITERS_A (PIX_PER_BLOCK / (TPB_A * PPT))   // 8
#define TPB_B 256
#define BINS_PER_T (BINS / TPB_B)          // 8 bins per pass_b thread
#define BLOSS_MAX 16.2f
#define BINW (BLOSS_MAX / (float)BINS)
#define B_CAP 15.9424f                     // -log(1-(1-1e-7f)) in f32 = -log(2*2^-24)
#define F_CAP 16.1181f                     // -log(1e-7f)
#define FIX_SCALE 16777216.0f              // 2^24 fixed-point scale for bin sums
#define INV_FIX (1.0 / 16777216.0)
#define SUM_MASK ((1ull << 44) - 1)

typedef float f32x4 __attribute__((ext_vector_type(4)));

// Pass A: one block per (sample, chunk), contiguous 64KB regions (round-3 map;
// the interleaved map regressed). Histogram = ONE u64 LDS atomic per pixel:
//   inc = ((u64)1 << 44) | (u64)(u32)(bl * 2^24)     (count | fixed-point sum)
// 2 copies selected by lane&1 -> even/odd lanes use disjoint bank pairs;
// ~4 bank-ops/bank/wave (minimum for 8B), same-address collisions ~0.25/wave.
// fg lanes add 0 (branchless). Theory: rounds 0-4 were DS-pipe bound on the
// scattered 32-bit atomic (~35 cy/wave-atomic x 4096/CU = the missing 140K cy).
__global__ __launch_bounds__(TPB_A, 8) void pass_a(
    const float* __restrict__ probs, const float* __restrict__ gt,
    unsigned long long* __restrict__ g_hist, float* __restrict__ f_part,
    float* __restrict__ b_part)
{
    __shared__ unsigned long long s_hist[BINS * COPIES];   // 32 KB
    __shared__ float s_redf[TPB_A / 64];
    __shared__ float s_redb[TPB_A / 64];

    const int tid = threadIdx.x;
    for (int j = tid; j < BINS * COPIES; j += TPB_A) s_hist[j] = 0ull;
    __syncthreads();

    const int blk = blockIdx.x;
    const int b = blk / CHUNKS;
    const int chunk = blk % CHUNKS;
    const float* p0 = probs + (size_t)b * 2 * NPIX;
    const float* p1 = p0 + NPIX;
    const float* gp = gt + (size_t)b * NPIX;
    const int base = chunk * PIX_PER_BLOCK;
    const float scale = (float)BINS / BLOSS_MAX;
    const int copy = tid & 1;

    float f_acc = 0.f, b_acc = 0.f;

    for (int it = 0; it < ITERS_A; ++it) {
        const int i = base + it * (TPB_A * PPT) + (tid << 2);
        const f32x4 a = *(const f32x4*)(p0 + i);
        const f32x4 c = *(const f32x4*)(p1 + i);
        const f32x4 g = *(const f32x4*)(gp + i);
        const float dv[PPT] = {c.x - a.x, c.y - a.y, c.z - a.z, c.w - a.w};
        const float gv[PPT] = {g.x, g.y, g.z, g.w};
        #pragma unroll
        for (int q = 0; q < PPT; ++q) {
            // -log(1-sigmoid(d)) = softplus(d); -log(sigmoid(d)) = softplus(d)-d
            const float d = dv[q];
            const float sp = fmaxf(d, 0.f) + __logf(1.f + __expf(-fabsf(d)));
            const bool fg = gv[q] > 0.5f;
            const float fl = fminf(sp - d, F_CAP);     // foreground loss (exact)
            const float bl = fminf(sp, B_CAP);         // background loss (exact)
            f_acc += fg ? fl : 0.f;
            b_acc += fg ? 0.f : bl;
            int bin = (int)(bl * scale);
            bin = bin < (BINS - 1) ? bin : (BINS - 1);
            // count in bits 44+, fixed-point (2^-24) sum in low 44 bits;
            // per (bin,copy,block): count<=16384<2^20, sum<2^43 -> no overflow
            const unsigned long long inc = fg ? 0ull
                : ((1ull << 44) | (unsigned long long)(unsigned)(bl * FIX_SCALE));
            atomicAdd(&s_hist[(bin << 1) | copy], inc);
        }
    }
    __syncthreads();

    // flush: merge 2 copies, plain coalesced u64 stores (16 KB/block)
    unsigned long long* dst = g_hist + ((size_t)b * CHUNKS + chunk) * BINS;
    for (int j = tid; j < BINS; j += TPB_A)
        dst[j] = s_hist[2 * j] + s_hist[2 * j + 1];

    // block-reduce f_acc / b_acc -> per-block slots (no atomics)
    #pragma unroll
    for (int o = 32; o > 0; o >>= 1) {
        f_acc += __shfl_down(f_acc, o, 64);
        b_acc += __shfl_down(b_acc, o, 64);
    }
    if ((tid & 63) == 0) { s_redf[tid >> 6] = f_acc; s_redb[tid >> 6] = b_acc; }
    __syncthreads();
    if (tid == 0) {
        float f = 0.f, bs = 0.f;
        #pragma unroll
        for (int w = 0; w < TPB_A / 64; ++w) { f += s_redf[w]; bs += s_redb[w]; }
        f_part[b * CHUNKS + chunk] = f;
        b_part[b * CHUNKS + chunk] = bs;
    }
}

// One block per sample. Sums the 64 chunk u64 histograms (8 bins/thread in
// registers, counts u32 + exact fixed-point sums u64), then top-k threshold
// via suffix scan; full bins above threshold contribute EXACT sums, only the
// partial threshold bin uses its own mean.
__global__ __launch_bounds__(TPB_B) void pass_b(
    const unsigned long long* __restrict__ g_hist, const float* __restrict__ f_part,
    const float* __restrict__ b_part, const float* __restrict__ gt_f_num,
    float* __restrict__ terms)
{
    __shared__ unsigned s_suf[TPB_B];
    __shared__ double s_wsuf[TPB_B];
    __shared__ double s_dsum;
    __shared__ double s_fb[2];

    const int b = blockIdx.x;
    const int t = threadIdx.x;

    unsigned cnt[BINS_PER_T];
    unsigned long long smf[BINS_PER_T];
    #pragma unroll
    for (int j = 0; j < BINS_PER_T; ++j) { cnt[j] = 0u; smf[j] = 0ull; }
    const unsigned long long* hb = g_hist + (size_t)b * CHUNKS * BINS + t * BINS_PER_T;
    for (int c = 0; c < CHUNKS; ++c) {
        #pragma unroll
        for (int j = 0; j < BINS_PER_T; ++j) {
            const unsigned long long v = hb[(size_t)c * BINS + j];  // coalesced 16KB sweep
            cnt[j] += (unsigned)(v >> 44);
            smf[j] += (v & SUM_MASK);
        }
    }

    // per-thread totals (exact values)
    unsigned c = 0; double w = 0.0;
    #pragma unroll
    for (int j = 0; j < BINS_PER_T; ++j) {
        c += cnt[j];
        w += (double)smf[j] * INV_FIX;
    }
    s_suf[t] = c; s_wsuf[t] = w;

    // reduce f/b per-block partials (first wave)
    if (t < 64) {   // CHUNKS == 64
        double ff = (double)f_part[b * CHUNKS + t];
        double bb = (double)b_part[b * CHUNKS + t];
        #pragma unroll
        for (int o = 32; o > 0; o >>= 1) {
            ff += __shfl_down(ff, o, 64);
            bb += __shfl_down(bb, o, 64);
        }
        if (t == 0) { s_fb[0] = ff; s_fb[1] = bb; }
    }
    __syncthreads();

    // Hillis-Steele inclusive suffix scan over 256 thread-chunks
    for (int off = 1; off < TPB_B; off <<= 1) {
        const unsigned ac = (t + off < TPB_B) ? s_suf[t + off] : 0u;
        const double aw = (t + off < TPB_B) ? s_wsuf[t + off] : 0.0;
        __syncthreads();
        s_suf[t] += ac; s_wsuf[t] += aw;
        __syncthreads();
    }

    const long long kk = (long long)gt_f_num[b];
    const unsigned long long n_pos = (unsigned long long)s_suf[0];
    const unsigned long long suf_me = s_suf[t];
    const unsigned long long suf_nx = (t + 1 < TPB_B) ? s_suf[t + 1] : 0ull;

    if (kk > 0 && (unsigned long long)kk < n_pos &&
        suf_nx < (unsigned long long)kk && (unsigned long long)kk <= suf_me) {
        // threshold bin is in my 8 bins; scan top-down (registers)
        unsigned long long cum = suf_nx;
        double W = (t + 1 < TPB_B) ? s_wsuf[t + 1] : 0.0;
        double part = 0.0;
        for (int j = BINS_PER_T - 1; j >= 0; --j) {
            const unsigned cc = cnt[j];
            const double sv = (double)smf[j] * INV_FIX;
            if (cum + cc >= (unsigned long long)kk) {
                // partial bin: use the bin's own mean (cc>0 at the crossing)
                part = (double)(kk - (long long)cum) * (sv / (double)cc);
                break;
            }
            cum += cc;
            W += sv;                                   // full bins: exact sums
        }
        s_dsum = W + part;
    }
    __syncthreads();

    if (t == 0) {
        const double S_total = s_fb[1];            // exact bg sum
        const double fs = s_fb[0];                 // exact fg sum
        const double gfn = (double)gt_f_num[b];
        double dsum, dnum;
        if (kk <= 0) { dsum = 0.0; dnum = 0.0; }
        else if ((unsigned long long)kk >= n_pos) { dsum = S_total; dnum = (double)n_pos; }
        else { dsum = s_dsum; dnum = (double)kk; }
        const double term = dsum / (dnum + 1e-16)
                          + fs / (gfn + 1e-16)
                          + (S_total - dsum) / ((double)NPIX + 1e-16);
        terms[b] = (float)term;
    }
}

__global__ void pass_c(const float* __restrict__ terms, float* __restrict__ out)
{
    if (threadIdx.x == 0 && blockIdx.x == 0) {
        float s = 0.f;
        #pragma unroll
        for (int i = 0; i < NB; ++i) s += terms[i];
        out[0] = s / (float)NB;
    }
}

extern "C" void kernel_launch(void* const* d_in, const int* in_sizes, int n_in,
                              void* d_out, int out_size, void* d_ws, size_t ws_size,
                              hipStream_t stream) {
    const float* probs = (const float*)d_in[0];
    const float* gt    = (const float*)d_in[1];
    const float* gfn   = (const float*)d_in[2];
    char* ws = (char*)d_ws;

    // Workspace layout (every byte read later is fully written first; no memset
    // needed even though ws is poisoned 0xAA before each launch):
    //   g_hist : NB*CHUNKS*BINS u64  (16 MB)  per-block u64 histograms
    //   f_part : NB*CHUNKS floats
    //   b_part : NB*CHUNKS floats
    //   terms  : NB floats
    const size_t hist_bytes = (size_t)NB * CHUNKS * BINS * sizeof(unsigned long long);
    unsigned long long* g_hist = (unsigned long long*)ws;
    float* f_part = (float*)(ws + hist_bytes);
    float* b_part = f_part + NB * CHUNKS;
    float* terms  = b_part + NB * CHUNKS;

    hipLaunchKernelGGL(pass_a, dim3(NB * CHUNKS), dim3(TPB_A), 0, stream,
                       probs, gt, g_hist, f_part, b_part);
    hipLaunchKernelGGL(pass_b, dim3(NB), dim3(TPB_B), 0, stream,
                       g_hist, f_part, b_part, gfn, terms);
    hipLaunchKernelGGL(pass_c, dim3(1), dim3(64), 0, stream,
                       terms, (float*)d_out);
}